// Round 1
// baseline (1356.978 us; speedup 1.0000x reference)
//
#include <hip/hip_runtime.h>
#include <hip/hip_bf16.h>

// Model: one_hot -> 3x Conv2D(5,(4,4),(1,2),SAME) -> [B,S=1024,D=20]
//        -> 3x causal self-attention -> flatten -> 3x Dense(10)
// B=64, L=8192, S=1024, D=20. All fp32 except int32 inputs.

#define B_ 64
#define L_ 8192
#define S_ 1024
#define D_ 20

// ---------------- conv1: one-hot input, CI=1 ----------------
// out [B,4,4096,5]; y[b,h,wo,c] = b1[c] + sum_{kh,kw} w1[kh,kw,0,c]*(inp[b,2wo-1+kw]==h-1+kh)
__global__ __launch_bounds__(256) void conv1_kernel(
    const int* __restrict__ inp, const float* __restrict__ W,
    const float* __restrict__ Bi, float* __restrict__ out) {
  __shared__ float ws[80];
  __shared__ float bs[5];
  if (threadIdx.x < 80) ws[threadIdx.x] = W[threadIdx.x];
  if (threadIdx.x < 5)  bs[threadIdx.x] = Bi[threadIdx.x];
  __syncthreads();
  int idx = blockIdx.x * 256 + threadIdx.x;   // (b, wo), wo in [0,4096)
  int b  = idx >> 12;
  int wo = idx & 4095;
  float acc[4][5];
#pragma unroll
  for (int h = 0; h < 4; ++h)
#pragma unroll
    for (int c = 0; c < 5; ++c) acc[h][c] = bs[c];
  const int* ib = inp + (size_t)b * L_;
#pragma unroll
  for (int kw = 0; kw < 4; ++kw) {
    int wi = 2 * wo - 1 + kw;
    if (wi >= 0 && wi < L_) {
      int v = ib[wi];
#pragma unroll
      for (int h = 0; h < 4; ++h) {
        int kh = v - h + 1;                   // hi = h-1+kh == v
        if (kh >= 0 && kh < 4) {
#pragma unroll
          for (int c = 0; c < 5; ++c) acc[h][c] += ws[(kh * 4 + kw) * 5 + c];
        }
      }
    }
  }
  float* ob = out + (size_t)b * 4 * 4096 * 5;
#pragma unroll
  for (int h = 0; h < 4; ++h)
#pragma unroll
    for (int c = 0; c < 5; ++c) ob[(h * 4096 + wo) * 5 + c] = acc[h][c];
}

// ---------------- conv2/conv3: CI=5, CO=5 ----------------
// TRANS=false: out [B,4,WOUT,5]; TRANS=true: out x[b][wo][h*5+c] (the transpose+reshape)
template <int WIN, bool TRANS>
__global__ __launch_bounds__(256) void conv5_kernel(
    const float* __restrict__ in, const float* __restrict__ W,
    const float* __restrict__ Bi, float* __restrict__ out) {
  constexpr int WOUT = WIN / 2;
  int idx = blockIdx.x * 256 + threadIdx.x;   // (b, wo)
  int b  = idx / WOUT;
  int wo = idx % WOUT;
  // stage all 80 inputs in registers
  float val[4][4][5];
#pragma unroll
  for (int hi = 0; hi < 4; ++hi) {
    const float* ir = in + ((size_t)b * 4 + hi) * WIN * 5;
#pragma unroll
    for (int kw = 0; kw < 4; ++kw) {
      int wi = 2 * wo - 1 + kw;
      bool ok = (wi >= 0 && wi < WIN);
#pragma unroll
      for (int ci = 0; ci < 5; ++ci) val[hi][kw][ci] = ok ? ir[wi * 5 + ci] : 0.f;
    }
  }
  float acc[4][5];
#pragma unroll
  for (int h = 0; h < 4; ++h)
#pragma unroll
    for (int c = 0; c < 5; ++c) acc[h][c] = Bi[c];
  // weights read with wave-uniform indices -> scalar loads
#pragma unroll
  for (int kh = 0; kh < 4; ++kh)
#pragma unroll
    for (int kw = 0; kw < 4; ++kw)
#pragma unroll
      for (int ci = 0; ci < 5; ++ci) {
        const float* wp = W + ((kh * 4 + kw) * 5 + ci) * 5;
        float w0 = wp[0], w1 = wp[1], w2 = wp[2], w3 = wp[3], w4 = wp[4];
#pragma unroll
        for (int h = 0; h < 4; ++h) {
          int hi = h - 1 + kh;
          if (hi >= 0 && hi < 4) {
            float x = val[hi][kw][ci];
            acc[h][0] += w0 * x; acc[h][1] += w1 * x; acc[h][2] += w2 * x;
            acc[h][3] += w3 * x; acc[h][4] += w4 * x;
          }
        }
      }
  if (TRANS) {
    float* ob = out + ((size_t)b * WOUT + wo) * 20;
#pragma unroll
    for (int h = 0; h < 4; ++h)
#pragma unroll
      for (int c = 0; c < 5; ++c) ob[h * 5 + c] = acc[h][c];
  } else {
    float* ob = out + (size_t)b * 4 * WOUT * 5;
#pragma unroll
    for (int h = 0; h < 4; ++h)
#pragma unroll
      for (int c = 0; c < 5; ++c) ob[(h * WOUT + wo) * 5 + c] = acc[h][c];
  }
}

// ---------------- Q/K/V projection ----------------
// X [B*S, 20]; Q scaled by 1/sqrt(20)
__global__ __launch_bounds__(256) void proj_kernel(
    const float* __restrict__ X,
    const float* __restrict__ Kw, const float* __restrict__ Qw,
    const float* __restrict__ Vw,
    float* __restrict__ Qo, float* __restrict__ Ko, float* __restrict__ Vo) {
  int r = blockIdx.x * 256 + threadIdx.x;
  const float* xr = X + (size_t)r * D_;
  float x[D_];
#pragma unroll
  for (int i = 0; i < D_; ++i) x[i] = xr[i];
  float q[D_], k[D_], v[D_];
#pragma unroll
  for (int j = 0; j < D_; ++j) { q[j] = 0.f; k[j] = 0.f; v[j] = 0.f; }
#pragma unroll
  for (int i = 0; i < D_; ++i) {
#pragma unroll
    for (int j = 0; j < D_; ++j) {
      q[j] += x[i] * Qw[i * D_ + j];
      k[j] += x[i] * Kw[i * D_ + j];
      v[j] += x[i] * Vw[i * D_ + j];
    }
  }
  const float sc = 0.22360679774997896f;  // 1/sqrt(20)
  float* qo = Qo + (size_t)r * D_;
  float* ko = Ko + (size_t)r * D_;
  float* vo = Vo + (size_t)r * D_;
#pragma unroll
  for (int j = 0; j < D_; ++j) { qo[j] = q[j] * sc; ko[j] = k[j]; vo[j] = v[j]; }
}

// ---------------- causal attention ----------------
// scores tiny (|s| << 1) -> softmax without max-subtraction is exact & safe.
// K/V rows read with wave-uniform t -> scalar loads (SMEM), no LDS needed.
__global__ __launch_bounds__(256) void attn_kernel(
    const float* __restrict__ Q, const float* __restrict__ K,
    const float* __restrict__ V, float* __restrict__ out) {
  const int b  = blockIdx.y;
  const int q0 = blockIdx.x << 8;
  const int q  = q0 + threadIdx.x;
  const size_t row = (size_t)b * S_ + q;
  const float* Qr = Q + row * D_;
  float qv[D_], O[D_];
#pragma unroll
  for (int d = 0; d < D_; ++d) { qv[d] = Qr[d]; O[d] = 0.f; }
  float l = 0.f;
  const float* Kb = K + (size_t)b * S_ * D_;
  const float* Vb = V + (size_t)b * S_ * D_;
  const int tend = q0 + 256;   // uniform bound; causal handled by predication
#pragma unroll 4
  for (int t = 0; t < tend; ++t) {
    const float* kr = Kb + t * D_;
    float s = 0.f;
#pragma unroll
    for (int d = 0; d < D_; ++d) s += qv[d] * kr[d];
    float p = (t <= q) ? __expf(s) : 0.f;
    l += p;
    const float* vr = Vb + t * D_;
#pragma unroll
    for (int d = 0; d < D_; ++d) O[d] += p * vr[d];
  }
  const float inv = 1.f / l;
  float* orow = out + row * D_;
#pragma unroll
  for (int d = 0; d < D_; ++d) orow[d] = O[d] * inv;
}

// ---------------- dense head ----------------
__global__ __launch_bounds__(256) void dense_kernel(
    const float* __restrict__ X,  // [64, 20480]
    const float* __restrict__ W1, const float* __restrict__ B1,
    const float* __restrict__ W2, const float* __restrict__ B2,
    const float* __restrict__ W3, const float* __restrict__ B3,
    float* __restrict__ out) {
  const int b = blockIdx.x;
  const float* xb = X + (size_t)b * 20480;
  float acc[10];
#pragma unroll
  for (int j = 0; j < 10; ++j) acc[j] = 0.f;
  for (int i = threadIdx.x; i < 20480; i += 256) {
    float v = xb[i];
    const float* wr = W1 + i * 10;
#pragma unroll
    for (int j = 0; j < 10; ++j) acc[j] += v * wr[j];
  }
  __shared__ float red[256][10];
#pragma unroll
  for (int j = 0; j < 10; ++j) red[threadIdx.x][j] = acc[j];
  __syncthreads();
  for (int off = 128; off > 0; off >>= 1) {
    if (threadIdx.x < (unsigned)off) {
#pragma unroll
      for (int j = 0; j < 10; ++j) red[threadIdx.x][j] += red[threadIdx.x + off][j];
    }
    __syncthreads();
  }
  __shared__ float y1[10], y2[10];
  if (threadIdx.x < 10) y1[threadIdx.x] = red[0][threadIdx.x] + B1[threadIdx.x];
  __syncthreads();
  if (threadIdx.x < 10) {
    int j = threadIdx.x;
    float s = B2[j];
#pragma unroll
    for (int i = 0; i < 10; ++i) s += y1[i] * W2[i * 10 + j];
    y2[j] = s;
  }
  __syncthreads();
  if (threadIdx.x < 10) {
    int j = threadIdx.x;
    float s = B3[j];
#pragma unroll
    for (int i = 0; i < 10; ++i) s += y2[i] * W3[i * 10 + j];
    out[b * 10 + j] = s;
  }
}

extern "C" void kernel_launch(void* const* d_in, const int* in_sizes, int n_in,
                              void* d_out, int out_size, void* d_ws, size_t ws_size,
                              hipStream_t stream) {
  const int*   inp = (const int*)d_in[0];
  const float* cw1 = (const float*)d_in[1];
  const float* cb1 = (const float*)d_in[2];
  const float* cw2 = (const float*)d_in[3];
  const float* cb2 = (const float*)d_in[4];
  const float* cw3 = (const float*)d_in[5];
  const float* cb3 = (const float*)d_in[6];
  const float* a1K = (const float*)d_in[7];
  const float* a1Q = (const float*)d_in[8];
  const float* a1V = (const float*)d_in[9];
  const float* a2K = (const float*)d_in[10];
  const float* a2Q = (const float*)d_in[11];
  const float* a2V = (const float*)d_in[12];
  const float* a3K = (const float*)d_in[13];
  const float* a3Q = (const float*)d_in[14];
  const float* a3V = (const float*)d_in[15];
  const float* dw1 = (const float*)d_in[16];
  const float* db1 = (const float*)d_in[17];
  const float* dw2 = (const float*)d_in[18];
  const float* db2 = (const float*)d_in[19];
  const float* dw3 = (const float*)d_in[20];
  const float* db3 = (const float*)d_in[21];
  float* outp = (float*)d_out;

  // workspace layout (floats); total 9,175,040 floats = 36.7 MB
  float* wsf = (float*)d_ws;
  float* c1 = wsf;                 // 5,242,880 floats [B,4,4096,5]
  float* c2 = wsf + 5242880;       // 2,621,440 floats [B,4,2048,5]
  float* x  = wsf + 7864320;       // 1,310,720 floats [B,S,20]
  float* q  = wsf;                 // reuse c1 region after conv2 consumed it
  float* k  = wsf + 1310720;
  float* v  = wsf + 2621440;
  float* o  = c2;                  // reuse c2 region after conv3 consumed it

  conv1_kernel<<<1024, 256, 0, stream>>>(inp, cw1, cb1, c1);
  conv5_kernel<4096, false><<<512, 256, 0, stream>>>(c1, cw2, cb2, c2);
  conv5_kernel<2048, true><<<256, 256, 0, stream>>>(c2, cw3, cb3, x);

  proj_kernel<<<256, 256, 0, stream>>>(x, a1K, a1Q, a1V, q, k, v);
  attn_kernel<<<dim3(4, 64), 256, 0, stream>>>(q, k, v, o);

  proj_kernel<<<256, 256, 0, stream>>>(o, a2K, a2Q, a2V, q, k, v);
  attn_kernel<<<dim3(4, 64), 256, 0, stream>>>(q, k, v, x);

  proj_kernel<<<256, 256, 0, stream>>>(x, a3K, a3Q, a3V, q, k, v);
  attn_kernel<<<dim3(4, 64), 256, 0, stream>>>(q, k, v, o);

  dense_kernel<<<64, 256, 0, stream>>>(o, dw1, db1, dw2, db2, dw3, db3, outp);
}

// Round 2
// 470.502 us; speedup vs baseline: 2.8841x; 2.8841x over previous
//
#include <hip/hip_runtime.h>
#include <hip/hip_bf16.h>

// Model: one_hot -> 3x Conv2D(5,(4,4),(1,2),SAME) -> [B,S=1024,D=20]
//        -> 3x causal self-attention -> flatten -> 3x Dense(10)
// B=64, L=8192, S=1024, D=20. All fp32 except int32 inputs.

#define B_ 64
#define L_ 8192
#define S_ 1024
#define D_ 20

// ---------------- conv1: one-hot input, CI=1 ----------------
__global__ __launch_bounds__(256) void conv1_kernel(
    const int* __restrict__ inp, const float* __restrict__ W,
    const float* __restrict__ Bi, float* __restrict__ out) {
  __shared__ float ws[80];
  __shared__ float bs[5];
  if (threadIdx.x < 80) ws[threadIdx.x] = W[threadIdx.x];
  if (threadIdx.x < 5)  bs[threadIdx.x] = Bi[threadIdx.x];
  __syncthreads();
  int idx = blockIdx.x * 256 + threadIdx.x;   // (b, wo), wo in [0,4096)
  int b  = idx >> 12;
  int wo = idx & 4095;
  float acc[4][5];
#pragma unroll
  for (int h = 0; h < 4; ++h)
#pragma unroll
    for (int c = 0; c < 5; ++c) acc[h][c] = bs[c];
  const int* ib = inp + (size_t)b * L_;
#pragma unroll
  for (int kw = 0; kw < 4; ++kw) {
    int wi = 2 * wo - 1 + kw;
    if (wi >= 0 && wi < L_) {
      int v = ib[wi];
#pragma unroll
      for (int h = 0; h < 4; ++h) {
        int kh = v - h + 1;                   // hi = h-1+kh == v
        if (kh >= 0 && kh < 4) {
#pragma unroll
          for (int c = 0; c < 5; ++c) acc[h][c] += ws[(kh * 4 + kw) * 5 + c];
        }
      }
    }
  }
  float* ob = out + (size_t)b * 4 * 4096 * 5;
#pragma unroll
  for (int h = 0; h < 4; ++h)
#pragma unroll
    for (int c = 0; c < 5; ++c) ob[(h * 4096 + wo) * 5 + c] = acc[h][c];
}

// ---------------- conv2/conv3: CI=5, CO=5, weights staged in LDS ----------------
template <int WIN, bool TRANS>
__global__ __launch_bounds__(256) void conv5_kernel(
    const float* __restrict__ in, const float* __restrict__ W,
    const float* __restrict__ Bi, float* __restrict__ out) {
  constexpr int WOUT = WIN / 2;
  __shared__ float ws[400];
  __shared__ float bs[5];
  for (int j = threadIdx.x; j < 400; j += 256) ws[j] = W[j];
  if (threadIdx.x < 5) bs[threadIdx.x] = Bi[threadIdx.x];
  __syncthreads();
  int idx = blockIdx.x * 256 + threadIdx.x;   // (b, wo)
  int b  = idx / WOUT;
  int wo = idx % WOUT;
  float val[4][4][5];
#pragma unroll
  for (int hi = 0; hi < 4; ++hi) {
    const float* ir = in + ((size_t)b * 4 + hi) * WIN * 5;
#pragma unroll
    for (int kw = 0; kw < 4; ++kw) {
      int wi = 2 * wo - 1 + kw;
      bool ok = (wi >= 0 && wi < WIN);
#pragma unroll
      for (int ci = 0; ci < 5; ++ci) val[hi][kw][ci] = ok ? ir[wi * 5 + ci] : 0.f;
    }
  }
  float acc[4][5];
#pragma unroll
  for (int h = 0; h < 4; ++h)
#pragma unroll
    for (int c = 0; c < 5; ++c) acc[h][c] = bs[c];
#pragma unroll
  for (int kh = 0; kh < 4; ++kh)
#pragma unroll
    for (int kw = 0; kw < 4; ++kw)
#pragma unroll
      for (int ci = 0; ci < 5; ++ci) {
        const float* wp = ws + ((kh * 4 + kw) * 5 + ci) * 5;
        float w0 = wp[0], w1 = wp[1], w2 = wp[2], w3 = wp[3], w4 = wp[4];
#pragma unroll
        for (int h = 0; h < 4; ++h) {
          int hi = h - 1 + kh;
          if (hi >= 0 && hi < 4) {
            float x = val[hi][kw][ci];
            acc[h][0] += w0 * x; acc[h][1] += w1 * x; acc[h][2] += w2 * x;
            acc[h][3] += w3 * x; acc[h][4] += w4 * x;
          }
        }
      }
  if (TRANS) {
    float* ob = out + ((size_t)b * WOUT + wo) * 20;
#pragma unroll
    for (int h = 0; h < 4; ++h)
#pragma unroll
      for (int c = 0; c < 5; ++c) ob[h * 5 + c] = acc[h][c];
  } else {
    float* ob = out + (size_t)b * 4 * WOUT * 5;
#pragma unroll
    for (int h = 0; h < 4; ++h)
#pragma unroll
      for (int c = 0; c < 5; ++c) ob[(h * WOUT + wo) * 5 + c] = acc[h][c];
  }
}

// ---------------- Q/K/V projection, weights staged in LDS ----------------
__global__ __launch_bounds__(256) void proj_kernel(
    const float* __restrict__ X,
    const float* __restrict__ Kw, const float* __restrict__ Qw,
    const float* __restrict__ Vw,
    float* __restrict__ Qo, float* __restrict__ Ko, float* __restrict__ Vo) {
  __shared__ float kw[400], qw[400], vw[400];
  for (int j = threadIdx.x; j < 400; j += 256) {
    kw[j] = Kw[j]; qw[j] = Qw[j]; vw[j] = Vw[j];
  }
  __syncthreads();
  int r = blockIdx.x * 256 + threadIdx.x;
  const float4* xr4 = (const float4*)(X + (size_t)r * D_);
  float x[D_];
#pragma unroll
  for (int i = 0; i < 5; ++i) {
    float4 t = xr4[i];
    x[4*i] = t.x; x[4*i+1] = t.y; x[4*i+2] = t.z; x[4*i+3] = t.w;
  }
  float q[D_], k[D_], v[D_];
#pragma unroll
  for (int j = 0; j < D_; ++j) { q[j] = 0.f; k[j] = 0.f; v[j] = 0.f; }
#pragma unroll
  for (int i = 0; i < D_; ++i) {
#pragma unroll
    for (int j = 0; j < D_; ++j) {
      q[j] += x[i] * qw[i * D_ + j];
      k[j] += x[i] * kw[i * D_ + j];
      v[j] += x[i] * vw[i * D_ + j];
    }
  }
  const float sc = 0.22360679774997896f;  // 1/sqrt(20)
  float4* qo = (float4*)(Qo + (size_t)r * D_);
  float4* ko = (float4*)(Ko + (size_t)r * D_);
  float4* vo = (float4*)(Vo + (size_t)r * D_);
#pragma unroll
  for (int i = 0; i < 5; ++i) {
    qo[i] = make_float4(q[4*i]*sc, q[4*i+1]*sc, q[4*i+2]*sc, q[4*i+3]*sc);
    ko[i] = make_float4(k[4*i],    k[4*i+1],    k[4*i+2],    k[4*i+3]);
    vo[i] = make_float4(v[4*i],    v[4*i+1],    v[4*i+2],    v[4*i+3]);
  }
}

// ---------------- causal attention ----------------
// 64 q rows per block; 4 threads per q row split t interleaved (t%4==c).
// K/V tiles (128 rows) staged in LDS; scores tiny -> no max-subtraction, so
// partial (l,O) merge across the 4 lanes is a plain butterfly add.
#define TQ_ 64
#define TT_ 128
__global__ __launch_bounds__(256) void attn_kernel(
    const float* __restrict__ Q, const float* __restrict__ K,
    const float* __restrict__ V, float* __restrict__ out) {
  const int b   = blockIdx.y;
  const int q0  = blockIdx.x * TQ_;
  const int tid = threadIdx.x;
  const int c   = tid & 3;
  const int q   = q0 + (tid >> 2);
  __shared__ float kt[TT_ * D_];
  __shared__ float vt[TT_ * D_];
  const size_t base = (size_t)b * S_ * D_;
  const float4* Qr4 = (const float4*)(Q + base + (size_t)q * D_);
  float qv[D_], O[D_];
#pragma unroll
  for (int i = 0; i < 5; ++i) {
    float4 t = Qr4[i];
    qv[4*i] = t.x; qv[4*i+1] = t.y; qv[4*i+2] = t.z; qv[4*i+3] = t.w;
  }
#pragma unroll
  for (int d = 0; d < D_; ++d) O[d] = 0.f;
  float l = 0.f;
  const int nt = q0 + TQ_;                 // max t needed is q0+TQ_-1
  const float4* ksrc = (const float4*)(K + base);
  const float4* vsrc = (const float4*)(V + base);
  float4* kd4 = (float4*)kt;
  float4* vd4 = (float4*)vt;
  for (int t0 = 0; t0 < nt; t0 += TT_) {
    __syncthreads();
    const int s4 = t0 * 5;                 // float4 index of tile start
    for (int j = tid; j < TT_ * 5; j += 256) {
      kd4[j] = ksrc[s4 + j];
      vd4[j] = vsrc[s4 + j];
    }
    __syncthreads();
    int iend = (nt - t0) >> 2;
    if (iend > TT_ / 4) iend = TT_ / 4;
#pragma unroll 2
    for (int i = 0; i < iend; ++i) {
      const int tl = 4 * i + c;
      const float* kr = kt + tl * D_;
      float s = 0.f;
#pragma unroll
      for (int d = 0; d < D_; ++d) s += qv[d] * kr[d];
      const int t = t0 + tl;
      float p = (t <= q) ? __expf(s) : 0.f;
      l += p;
      const float* vr = vt + tl * D_;
#pragma unroll
      for (int d = 0; d < D_; ++d) O[d] += p * vr[d];
    }
  }
  // merge partials across the 4 lanes of each q-group
#pragma unroll
  for (int m = 1; m <= 2; m <<= 1) {
    l += __shfl_xor(l, m, 64);
#pragma unroll
    for (int d = 0; d < D_; ++d) O[d] += __shfl_xor(O[d], m, 64);
  }
  const float inv = 1.f / l;
  float* orow = out + base + (size_t)q * D_ + c * 5;
#pragma unroll
  for (int j = 0; j < 5; ++j) orow[j] = O[c * 5 + j] * inv;
}

// ---------------- dense head: stage 1 (partials) ----------------
__global__ __launch_bounds__(256) void dense1_partial(
    const float* __restrict__ X,   // [64, 20480]
    const float* __restrict__ W1,  // [20480, 10]
    float* __restrict__ part) {    // [64, 4, 10]
  const int b = blockIdx.x;
  const int s = blockIdx.y;
  const float* xb = X + (size_t)b * 20480 + s * 5120;
  const float* wb = W1 + (size_t)s * 5120 * 10;
  float acc[10];
#pragma unroll
  for (int j = 0; j < 10; ++j) acc[j] = 0.f;
  for (int i = threadIdx.x; i < 5120; i += 256) {
    float v = xb[i];
    const float* wr = wb + i * 10;
#pragma unroll
    for (int j = 0; j < 10; ++j) acc[j] += v * wr[j];
  }
  __shared__ float red[256][10];
#pragma unroll
  for (int j = 0; j < 10; ++j) red[threadIdx.x][j] = acc[j];
  __syncthreads();
  for (int off = 128; off > 0; off >>= 1) {
    if (threadIdx.x < (unsigned)off) {
#pragma unroll
      for (int j = 0; j < 10; ++j) red[threadIdx.x][j] += red[threadIdx.x + off][j];
    }
    __syncthreads();
  }
  if (threadIdx.x < 10) part[(b * 4 + s) * 10 + threadIdx.x] = red[0][threadIdx.x];
}

// ---------------- dense head: stage 2 (combine + dense2/3) ----------------
__global__ __launch_bounds__(64) void dense_final(
    const float* __restrict__ part,
    const float* __restrict__ B1,
    const float* __restrict__ W2, const float* __restrict__ B2,
    const float* __restrict__ W3, const float* __restrict__ B3,
    float* __restrict__ out) {
  const int b = blockIdx.x;
  __shared__ float y1[10], y2[10];
  if (threadIdx.x < 10) {
    int j = threadIdx.x;
    y1[j] = part[(b*4+0)*10 + j] + part[(b*4+1)*10 + j] +
            part[(b*4+2)*10 + j] + part[(b*4+3)*10 + j] + B1[j];
  }
  __syncthreads();
  if (threadIdx.x < 10) {
    int j = threadIdx.x;
    float s = B2[j];
#pragma unroll
    for (int i = 0; i < 10; ++i) s += y1[i] * W2[i * 10 + j];
    y2[j] = s;
  }
  __syncthreads();
  if (threadIdx.x < 10) {
    int j = threadIdx.x;
    float s = B3[j];
#pragma unroll
    for (int i = 0; i < 10; ++i) s += y2[i] * W3[i * 10 + j];
    out[b * 10 + j] = s;
  }
}

extern "C" void kernel_launch(void* const* d_in, const int* in_sizes, int n_in,
                              void* d_out, int out_size, void* d_ws, size_t ws_size,
                              hipStream_t stream) {
  const int*   inp = (const int*)d_in[0];
  const float* cw1 = (const float*)d_in[1];
  const float* cb1 = (const float*)d_in[2];
  const float* cw2 = (const float*)d_in[3];
  const float* cb2 = (const float*)d_in[4];
  const float* cw3 = (const float*)d_in[5];
  const float* cb3 = (const float*)d_in[6];
  const float* a1K = (const float*)d_in[7];
  const float* a1Q = (const float*)d_in[8];
  const float* a1V = (const float*)d_in[9];
  const float* a2K = (const float*)d_in[10];
  const float* a2Q = (const float*)d_in[11];
  const float* a2V = (const float*)d_in[12];
  const float* a3K = (const float*)d_in[13];
  const float* a3Q = (const float*)d_in[14];
  const float* a3V = (const float*)d_in[15];
  const float* dw1 = (const float*)d_in[16];
  const float* db1 = (const float*)d_in[17];
  const float* dw2 = (const float*)d_in[18];
  const float* db2 = (const float*)d_in[19];
  const float* dw3 = (const float*)d_in[20];
  const float* db3 = (const float*)d_in[21];
  float* outp = (float*)d_out;

  // workspace layout (floats)
  float* wsf  = (float*)d_ws;
  float* c1   = wsf;                 // [B,4,4096,5]  5,242,880 floats
  float* c2   = wsf + 5242880;       // [B,4,2048,5]  2,621,440 floats
  float* x    = wsf + 7864320;       // [B,S,20]      1,310,720 floats
  float* q    = wsf;                 // reuse c1 after conv2
  float* k    = wsf + 1310720;
  float* v    = wsf + 2621440;
  float* part = wsf + 3932160;       // [64,4,10] = 2,560 floats
  float* o    = c2;                  // reuse c2 after conv3

  conv1_kernel<<<1024, 256, 0, stream>>>(inp, cw1, cb1, c1);
  conv5_kernel<4096, false><<<512, 256, 0, stream>>>(c1, cw2, cb2, c2);
  conv5_kernel<2048, true><<<256, 256, 0, stream>>>(c2, cw3, cb3, x);

  proj_kernel<<<256, 256, 0, stream>>>(x, a1K, a1Q, a1V, q, k, v);
  attn_kernel<<<dim3(16, 64), 256, 0, stream>>>(q, k, v, o);

  proj_kernel<<<256, 256, 0, stream>>>(o, a2K, a2Q, a2V, q, k, v);
  attn_kernel<<<dim3(16, 64), 256, 0, stream>>>(q, k, v, x);

  proj_kernel<<<256, 256, 0, stream>>>(x, a3K, a3Q, a3V, q, k, v);
  attn_kernel<<<dim3(16, 64), 256, 0, stream>>>(q, k, v, o);

  dense1_partial<<<dim3(64, 4), 256, 0, stream>>>(o, dw1, part);
  dense_final<<<64, 64, 0, stream>>>(part, db1, dw2, db2, dw3, db3, outp);
}